// Round 11
// baseline (604.941 us; speedup 1.0000x reference)
//
#include <hip/hip_runtime.h>

#define N_NODES 100000
#define N_EDGES 3200000
#define DDIM 256
#define SLOTS 64         // per-node record capacity (Poisson(32), max deg ~60)
#define OVF_CAP 4096     // spill list capacity (expected use: 0)

typedef short s16x8 __attribute__((ext_vector_type(8)));
typedef float f32x4 __attribute__((ext_vector_type(4)));
typedef float f32x2 __attribute__((ext_vector_type(2)));

__device__ __forceinline__ unsigned short f32_to_bf16(float f) {
    union { float f; unsigned int u; } c; c.f = f;
    unsigned int u = c.u;
    unsigned int r = u + 0x7fffu + ((u >> 16) & 1u);  // RNE
    return (unsigned short)(r >> 16);
}
__device__ __forceinline__ float bl16(unsigned int u) {   // low bf16 of dword -> f32
    union { unsigned int x; float f; } c; c.x = u << 16; return c.f;
}
__device__ __forceinline__ float bh16(unsigned int u) {   // high bf16 of dword -> f32
    union { unsigned int x; float f; } c; c.x = u & 0xffff0000u; return c.f;
}

// ---------------- W -> Wt (bf16, transposed to [n][k]) ----------------
__global__ __launch_bounds__(256) void prep_w(const float* __restrict__ W,
                                              unsigned short* __restrict__ Wt) {
    __shared__ float tile[32][33];
    const int tx = threadIdx.x & 31;
    const int ty = threadIdx.x >> 5;
    const int n0 = blockIdx.x * 32;
    const int k0 = blockIdx.y * 32;
    for (int i = 0; i < 32; i += 8)
        tile[ty + i][tx] = W[(size_t)(k0 + ty + i) * DDIM + n0 + tx];
    __syncthreads();
    for (int i = 0; i < 32; i += 8)
        Wt[(size_t)(n0 + ty + i) * DDIM + k0 + tx] = f32_to_bf16(tile[tx][ty + i]);
}

// ---------------- MFMA bf16 GEMM: Xb[N,256] = bf16(A) @ bf16(W) ----------------
__global__ __launch_bounds__(256) void gemm_mfma(const float* __restrict__ A,
                                                 const unsigned short* __restrict__ Wt,
                                                 unsigned short* __restrict__ Xb) {
    __shared__ unsigned short As[64][DDIM + 8];
    const int tid = threadIdx.x;
    const int rowBase = blockIdx.x * 64;

#pragma unroll
    for (int p = 0; p < 16; ++p) {
        const int flat = p * 256 + tid;
        const int row = flat >> 6;
        const int k4 = (flat & 63) * 4;
        const int gr = rowBase + row;
        float4 v = make_float4(0.f, 0.f, 0.f, 0.f);
        if (gr < N_NODES) v = *(const float4*)&A[(size_t)gr * DDIM + k4];
        ushort4 h;
        h.x = f32_to_bf16(v.x); h.y = f32_to_bf16(v.y);
        h.z = f32_to_bf16(v.z); h.w = f32_to_bf16(v.w);
        *(ushort4*)&As[row][k4] = h;
    }
    __syncthreads();

    const int wave = tid >> 6;
    const int lane = tid & 63;
    const int lrow = lane & 15;
    const int quad = lane >> 4;
    const int cb = wave * 64;

    f32x4 acc[4][4] = {};

#pragma unroll
    for (int ks = 0; ks < 8; ++ks) {
        const int k0 = ks * 32 + quad * 8;
        s16x8 a[4], b[4];
#pragma unroll
        for (int ri = 0; ri < 4; ++ri)
            a[ri] = *(const s16x8*)&As[ri * 16 + lrow][k0];
#pragma unroll
        for (int ci = 0; ci < 4; ++ci)
            b[ci] = *(const s16x8*)&Wt[(size_t)(cb + ci * 16 + lrow) * DDIM + k0];
#pragma unroll
        for (int ri = 0; ri < 4; ++ri)
#pragma unroll
            for (int ci = 0; ci < 4; ++ci)
                acc[ri][ci] = __builtin_amdgcn_mfma_f32_16x16x32_bf16(a[ri], b[ci], acc[ri][ci], 0, 0, 0);
    }

    __syncthreads();   // done reading As as A-tile; reuse it as C-tile
#pragma unroll
    for (int ri = 0; ri < 4; ++ri)
#pragma unroll
        for (int rr = 0; rr < 4; ++rr)
#pragma unroll
            for (int ci = 0; ci < 4; ++ci)
                As[ri * 16 + quad * 4 + rr][cb + ci * 16 + lrow] =
                    f32_to_bf16(acc[ri][ci][rr]);
    __syncthreads();

    // stream out: 64 rows x 256 cols bf16 = 32KB, 16B chunks, fully coalesced
#pragma unroll
    for (int it = 0; it < 8; ++it) {
        const int flat = it * 256 + tid;     // 2048 chunks of 8 ushorts
        const int row  = flat >> 5;          // 32 chunks per row
        const int c8   = (flat & 31) * 8;
        const int grow = rowBase + row;
        if (grow < N_NODES)
            *(s16x8*)&Xb[(size_t)grow * DDIM + c8] = *(const s16x8*)&As[row][c8];
    }
}

// ---------------- one-shot edge scatter into fixed-capacity slot table ------
// Replaces the entire CSR build (hist+scan+bin+refine). Record = (src, val)
// packed in 8B; position = atomic ticket on cnt[dst]. Order within a node is
// irrelevant (sum is commutative). Rare ticket>=SLOTS spills to ovf list.
__global__ __launch_bounds__(256) void scatter_edges(const int* __restrict__ esrc,
                                                     const int* __restrict__ edst,
                                                     const float* __restrict__ evals,
                                                     int* __restrict__ cnt,
                                                     int* __restrict__ ovfcnt,
                                                     int4* __restrict__ ovf,
                                                     long long* __restrict__ slots) {
    const int stride = gridDim.x * 256;
    for (int e = blockIdx.x * 256 + threadIdx.x; e < N_EDGES; e += stride) {
        const int d = edst[e];
        const int s = esrc[e];
        const unsigned int vb = (unsigned int)__float_as_int(evals[e]);
        const int t = atomicAdd(&cnt[d], 1);
        if (t < SLOTS) {
            slots[((size_t)d << 6) + t] = (long long)(((unsigned long long)vb << 32) |
                                                      (unsigned int)s);
        } else {
            const int o = atomicAdd(ovfcnt, 1);
            if (o < OVF_CAP) ovf[o] = make_int4(d, s, (int)vb, 0);
        }
    }
}

// ---------------- SpMM gather from slot table, half-dims per blockIdx.y -----
#define HEDGE(q) { a0 += v##q * bl16(h##q); a1 += v##q * bh16(h##q); }

__global__ __launch_bounds__(256) void spmm_half(const unsigned short* __restrict__ xb,
                                                 const int* __restrict__ cnt,
                                                 const long long* __restrict__ slots,
                                                 const int* __restrict__ ovfcnt,
                                                 const int4* __restrict__ ovf,
                                                 float* __restrict__ out) {
    const int node = blockIdx.x * 4 + (threadIdx.x >> 6);
    const int lane = threadIdx.x & 63;
    const int dimoff = blockIdx.y << 7;

    const int cn = min(cnt[node], SLOTS);      // in-slot record count (<= 64)
    const unsigned short* xcol = xb + dimoff + lane * 2;   // + src*DDIM
    float a0 = 0.f, a1 = 0.f;

    // one chunk: cn <= 64 records, lane-loaded then shfl-broadcast
    int s_l = 0;
    float v_l = 0.f;
    if (lane < cn) {
        const long long q = slots[((size_t)node << 6) + lane];
        s_l = (int)(unsigned int)q;
        v_l = __int_as_float((int)(q >> 32));
    }
    int j = 0;
    for (; j + 8 <= cn; j += 8) {
        const int s0 = __shfl(s_l, j + 0);
        const int s1 = __shfl(s_l, j + 1);
        const int s2 = __shfl(s_l, j + 2);
        const int s3 = __shfl(s_l, j + 3);
        const int s4 = __shfl(s_l, j + 4);
        const int s5 = __shfl(s_l, j + 5);
        const int s6 = __shfl(s_l, j + 6);
        const int s7 = __shfl(s_l, j + 7);
        const float v0 = __shfl(v_l, j + 0);
        const float v1 = __shfl(v_l, j + 1);
        const float v2 = __shfl(v_l, j + 2);
        const float v3 = __shfl(v_l, j + 3);
        const float v4 = __shfl(v_l, j + 4);
        const float v5 = __shfl(v_l, j + 5);
        const float v6 = __shfl(v_l, j + 6);
        const float v7 = __shfl(v_l, j + 7);
        const unsigned int h0 = *(const unsigned int*)&xcol[(size_t)s0 * DDIM];
        const unsigned int h1 = *(const unsigned int*)&xcol[(size_t)s1 * DDIM];
        const unsigned int h2 = *(const unsigned int*)&xcol[(size_t)s2 * DDIM];
        const unsigned int h3 = *(const unsigned int*)&xcol[(size_t)s3 * DDIM];
        const unsigned int h4 = *(const unsigned int*)&xcol[(size_t)s4 * DDIM];
        const unsigned int h5 = *(const unsigned int*)&xcol[(size_t)s5 * DDIM];
        const unsigned int h6 = *(const unsigned int*)&xcol[(size_t)s6 * DDIM];
        const unsigned int h7 = *(const unsigned int*)&xcol[(size_t)s7 * DDIM];
        HEDGE(0) HEDGE(1) HEDGE(2) HEDGE(3)
        HEDGE(4) HEDGE(5) HEDGE(6) HEDGE(7)
    }
    for (; j < cn; ++j) {
        const int s = __shfl(s_l, j);
        const float v = __shfl(v_l, j);
        const unsigned int h = *(const unsigned int*)&xcol[(size_t)s * DDIM];
        a0 += v * bl16(h); a1 += v * bh16(h);
    }

    // rare overflow records (pre-ReLU, correctness path; expected count 0)
    const int no = min(*ovfcnt, OVF_CAP);
    if (no > 0) {
        for (int i = 0; i < no; ++i) {
            const int4 r = ovf[i];
            if (r.x == node) {
                const unsigned int h = *(const unsigned int*)&xcol[(size_t)r.y * DDIM];
                const float v = __int_as_float(r.z);
                a0 += v * bl16(h); a1 += v * bh16(h);
            }
        }
    }

    f32x2 o;
    o[0] = fmaxf(a0, 0.f);
    o[1] = fmaxf(a1, 0.f);
    __builtin_nontemporal_store(o, (f32x2*)&out[(size_t)node * DDIM + dimoff + lane * 2]);
}
#undef HEDGE

extern "C" void kernel_launch(void* const* d_in, const int* in_sizes, int n_in,
                              void* d_out, int out_size, void* d_ws, size_t ws_size,
                              hipStream_t stream) {
    const float* inputs = (const float*)d_in[0];
    const float* weight = (const float*)d_in[1];
    const int* esrc     = (const int*)d_in[2];
    const int* edst     = (const int*)d_in[3];
    const float* evals  = (const float*)d_in[4];
    float* out = (float*)d_out;

    // workspace layout (<= 103.0 MB; previous layouts used 103.4)
    unsigned short* xb = (unsigned short*)d_ws;                  // 51.2 MB
    unsigned short* Wt = xb + (size_t)N_NODES * DDIM;            // 128 KB
    int* cnt    = (int*)(Wt + DDIM * DDIM);                      // 100000 ints
    int* ovfcnt = cnt + N_NODES;                                 // 1 int (+3 pad)
    int4* ovf   = (int4*)(cnt + N_NODES + 4);                    // 64 KB, 16B-aligned
    long long* slots = (long long*)(ovf + OVF_CAP);              // 51.2 MB

    // 1) Wt = bf16(W^T)
    prep_w<<<dim3(8, 8), 256, 0, stream>>>(weight, Wt);

    // 2) xb = bf16(inputs @ W) via MFMA, coalesced epilogue
    gemm_mfma<<<(N_NODES + 63) / 64, 256, 0, stream>>>(inputs, Wt, xb);

    // 3) one-shot scatter build (replaces hist+scan+bin+refine)
    (void)hipMemsetAsync(cnt, 0, (N_NODES + 4) * sizeof(int), stream);
    scatter_edges<<<2048, 256, 0, stream>>>(esrc, edst, evals, cnt, ovfcnt, ovf, slots);

    // 4) gather in one dispatch, two half-dim planes via blockIdx.y
    spmm_half<<<dim3(N_NODES / 4, 2), 256, 0, stream>>>(xb, cnt, slots, ovfcnt, ovf, out);
}